// Round 5
// baseline (273.573 us; speedup 1.0000x reference)
//
#include <hip/hip_runtime.h>

#define RES   256
#define NCH   128    // C*F
#define NC    16
#define NPK   64     // packed uint32 per (p,y,x) position = NCH/2
#define NBINS 32768  // 32^3 Morton cells
#define RECW  12     // uint32 words per point record (48B)

__device__ __forceinline__ unsigned f32_to_bf16_rne(float f) {
    unsigned u = __float_as_uint(f);
    return (u + 0x7FFFu + ((u >> 16) & 1u)) >> 16;
}
__device__ __forceinline__ float bf16_lo(unsigned w) { return __uint_as_float(w << 16); }
__device__ __forceinline__ float bf16_hi(unsigned w) { return __uint_as_float(w & 0xFFFF0000u); }
__device__ __forceinline__ float reflectf(float v) {
    float r = fabsf(v);
    r = fmodf(r, 510.0f);
    return (r > 255.0f) ? (510.0f - r) : r;
}
__device__ __forceinline__ unsigned spread5(unsigned v) {  // 5 bits -> stride 3
    return (v & 1u) | ((v & 2u) << 2) | ((v & 4u) << 4) | ((v & 8u) << 6) | ((v & 16u) << 8);
}
__device__ __forceinline__ int cell_of(int x0, int x1, int x2) {
    return (int)(spread5((unsigned)x0 >> 3) | (spread5((unsigned)x1 >> 3) << 1)
               | (spread5((unsigned)x2 >> 3) << 2));
}
__device__ __forceinline__ int point_cell(const float* __restrict__ coords, int i) {
    const int a = (int)reflectf((coords[3 * (size_t)i + 0] + 1.0f) * 127.5f);
    const int b = (int)reflectf((coords[3 * (size_t)i + 1] + 1.0f) * 127.5f);
    const int d = (int)reflectf((coords[3 * (size_t)i + 2] + 1.0f) * 127.5f);
    return cell_of(a, b, d);
}

// ---------------------------------------------------------------------------
// LDS-free streaming transpose+pack:
// f32 [3][128][256][256] -> bf16-pair uint32 [3][256][256][64].
// Block = (x-half, y, p); 256 threads: half handles channel groups 0..7,
// half 8..15, each over 128 x. All reads wave-coalesced 256B; uint4 stores.
// ---------------------------------------------------------------------------
__global__ __launch_bounds__(256) void fg_transpose(
    const float* __restrict__ in, unsigned* __restrict__ out)
{
    const int tid = threadIdx.x;
    const int x   = blockIdx.x * 128 + (tid & 127);
    const int g0  = (tid >> 7) * 8;             // 0 or 8
    const int y   = blockIdx.y;
    const int p   = blockIdx.z;

    const float* src = in + (((size_t)p * NCH) * RES + y) * RES + x;  // q=0
    unsigned* dst = out + (((size_t)p * RES + y) * RES + x) * NPK;

    #pragma unroll
    for (int g = g0; g < g0 + 8; ++g) {
        float v[8];
        #pragma unroll
        for (int j = 0; j < 8; ++j)
            v[j] = src[(size_t)(g * 8 + j) * (RES * RES)];
        uint4 w;
        w.x = f32_to_bf16_rne(v[0]) | (f32_to_bf16_rne(v[1]) << 16);
        w.y = f32_to_bf16_rne(v[2]) | (f32_to_bf16_rne(v[3]) << 16);
        w.z = f32_to_bf16_rne(v[4]) | (f32_to_bf16_rne(v[5]) << 16);
        w.w = f32_to_bf16_rne(v[6]) | (f32_to_bf16_rne(v[7]) << 16);
        *(uint4*)(dst + 4 * g) = w;
    }
}

// ---------------------------------------------------------------------------
// Morton-cell histogram
// ---------------------------------------------------------------------------
__global__ __launch_bounds__(256) void fg_hist(
    const float* __restrict__ coords, unsigned* __restrict__ hist, int n)
{
    const int i = blockIdx.x * 256 + threadIdx.x;
    if (i >= n) return;
    atomicAdd(&hist[point_cell(coords, i)], 1u);
}

// ---------------------------------------------------------------------------
// Exclusive scan over 32768 bins (one 1024-thread block) + frp precompute
// ---------------------------------------------------------------------------
__global__ __launch_bounds__(1024) void fg_scan(
    const unsigned* __restrict__ hist, unsigned* __restrict__ cursor,
    const float* __restrict__ freqs, float* __restrict__ frp)
{
    __shared__ unsigned wtot[16];
    const int t = threadIdx.x;
    const int lane = t & 63;
    const int wid = t >> 6;
    unsigned loc[32];
    unsigned sum = 0;
    #pragma unroll
    for (int k = 0; k < 8; ++k) {
        const uint4 u = ((const uint4*)hist)[t * 8 + k];
        loc[4 * k + 0] = u.x; loc[4 * k + 1] = u.y;
        loc[4 * k + 2] = u.z; loc[4 * k + 3] = u.w;
        sum += u.x + u.y + u.z + u.w;
    }
    unsigned v = sum;
    #pragma unroll
    for (int off = 1; off < 64; off <<= 1) {
        const unsigned u = __shfl_up(v, off);
        if (lane >= off) v += u;
    }
    if (lane == 63) wtot[wid] = v;
    __syncthreads();
    unsigned base = 0;
    #pragma unroll
    for (int w = 0; w < 16; ++w) base += (w < wid) ? wtot[w] : 0u;
    unsigned run = base + (v - sum);
    #pragma unroll
    for (int k = 0; k < 32; ++k) { cursor[t * 32 + k] = run; run += loc[k]; }
    if (t < 128) {
        const float f = fminf(fmaxf(freqs[t], 0.0f), 1.0f);
        frp[t] = __builtin_amdgcn_exp2f(f * 8.0f) - 0.5f;
    }
}

// ---------------------------------------------------------------------------
// Scatter: compute per-point record (3 plane byte-offsets, 3 weights,
// 3 phase coefs, orig index) and write to Morton-sorted position.
// x1=x0+1 / y1=y0+1 is always safe for the consumer: when x0==255 the
// fractional weight is exactly 0, so the (in-ws, 64KB-max) over-read
// contributes 0 (hist region holds small uints -> never NaN/Inf).
// ---------------------------------------------------------------------------
__global__ __launch_bounds__(256) void fg_scatter(
    const float* __restrict__ coords, unsigned* __restrict__ cursor,
    unsigned* __restrict__ rec, int n)
{
    const int i = blockIdx.x * 256 + threadIdx.x;
    if (i >= n) return;
    int   x0[3];
    float w[3], A[3];
    #pragma unroll
    for (int k = 0; k < 3; ++k) {
        const float pts = (coords[3 * (size_t)i + k] + 1.0f) * 127.5f;
        const float r = reflectf(pts);
        const float fl = floorf(r);
        x0[k] = (int)fl;
        w[k]  = r - fl;
        A[k]  = (pts + 0.5f) * (1.0f / 512.0f);
    }
    const unsigned pos = atomicAdd(&cursor[cell_of(x0[0], x0[1], x0[2])], 1u);
    unsigned* o = rec + (size_t)pos * RECW;
    uint4 r0, r1, r2;
    r0.x = (unsigned)((x0[2] * 256 + x0[1]) * 256);            // plane0: y=d2,x=d1
    r0.y = (unsigned)((65536 + x0[2] * 256 + x0[0]) * 256);    // plane1: y=d2,x=d0
    r0.z = (unsigned)((131072 + x0[1] * 256 + x0[0]) * 256);   // plane2: y=d1,x=d0
    r0.w = __float_as_uint(w[0]);
    r1.x = __float_as_uint(w[1]);
    r1.y = __float_as_uint(w[2]);
    r1.z = __float_as_uint(A[0]);
    r1.w = __float_as_uint(A[1]);
    r2.x = __float_as_uint(A[2]);
    r2.y = (unsigned)i;
    r2.z = 0u; r2.w = 0u;
    *(uint4*)(o + 0) = r0;
    *(uint4*)(o + 4) = r1;
    *(uint4*)(o + 8) = r2;
}

// ---------------------------------------------------------------------------
// Main kernel: packed bf16 grid, Morton-sorted records, XCD-chunk swizzle.
// 16 lanes per point; lane c owns output channel c (q = c*8+f).
// ---------------------------------------------------------------------------
__global__ __launch_bounds__(256) void fg_main_bf16(
    const unsigned* __restrict__ grid,     // [3][256][256][64] bf16-pairs
    const float* __restrict__ frp_in,      // 128 precomputed (fr+0.5)
    const unsigned* __restrict__ rec,
    float* __restrict__ out, int n)
{
    const int t = threadIdx.x;
    const int c = t & 15;
    int b = blockIdx.x;
    {
        const int G = gridDim.x;
        const int chunk = G >> 3;
        const int lim = chunk << 3;
        if (b < lim) b = (b & 7) * chunk + (b >> 3);  // contiguous range per XCD
    }
    const int slot = b * 16 + (t >> 4);
    if (slot >= n) return;

    const unsigned* o = rec + (size_t)slot * RECW;
    const uint4 r0 = *(const uint4*)(o + 0);
    const uint4 r1 = *(const uint4*)(o + 4);
    const uint4 r2 = *(const uint4*)(o + 8);
    const unsigned off[3] = {r0.x, r0.y, r0.z};
    const float w0 = __uint_as_float(r0.w);
    const float w1 = __uint_as_float(r1.x);
    const float w2 = __uint_as_float(r1.y);
    const float A[3] = {__uint_as_float(r1.z), __uint_as_float(r1.w),
                        __uint_as_float(r2.x)};
    const int i = (int)r2.y;

    float frp[8];
    *(float4*)(frp + 0) = *(const float4*)(frp_in + c * 8 + 0);
    *(float4*)(frp + 4) = *(const float4*)(frp_in + c * 8 + 4);

    const char* gB = (const char*)grid;
    const unsigned claneoff = (unsigned)(c * 16);
    float acc = 0.0f;

    #pragma unroll
    for (int p = 0; p < 3; ++p) {
        const float wx = (p == 0) ? w1 : w0;
        const float wy = (p == 2) ? w1 : w2;
        const float ox = 1.0f - wx, oy = 1.0f - wy;
        const float w00 = ox * oy, w01 = wx * oy, w10 = ox * wy, w11 = wx * wy;

        const unsigned v0 = off[p] + claneoff;
        const unsigned v1 = v0 + 65536u;              // y+1 row
        const uint4 g00 = *(const uint4*)(gB + v0);
        const uint4 g01 = *(const uint4*)(gB + v0 + 256);  // x+1
        const uint4 g10 = *(const uint4*)(gB + v1);
        const uint4 g11 = *(const uint4*)(gB + v1 + 256);
        const unsigned a0[4] = {g00.x, g00.y, g00.z, g00.w};
        const unsigned a1[4] = {g01.x, g01.y, g01.z, g01.w};
        const unsigned a2[4] = {g10.x, g10.y, g10.z, g10.w};
        const unsigned a3[4] = {g11.x, g11.y, g11.z, g11.w};

        #pragma unroll
        for (int jj = 0; jj < 4; ++jj) {
            const float clo = w00 * bf16_lo(a0[jj]) + w01 * bf16_lo(a1[jj])
                            + w10 * bf16_lo(a2[jj]) + w11 * bf16_lo(a3[jj]);
            const float chi = w00 * bf16_hi(a0[jj]) + w01 * bf16_hi(a1[jj])
                            + w10 * bf16_hi(a2[jj]) + w11 * bf16_hi(a3[jj]);
            const float rl = __builtin_amdgcn_fractf(A[p] * frp[2 * jj + 0]);
            const float rh = __builtin_amdgcn_fractf(A[p] * frp[2 * jj + 1]);
            acc += clo * __builtin_amdgcn_cosf(rl);
            acc += chi * __builtin_amdgcn_cosf(rh);
        }
    }

    out[(size_t)i * NC + c] = 2.0f * acc;
}

// Fallback (no workspace): direct f32 channel-major gather.
__global__ __launch_bounds__(256) void fg_main_f32(
    const float* __restrict__ coords,
    const float* __restrict__ grid,
    const float* __restrict__ freqs,
    float* __restrict__ out, int n)
{
    const int t = threadIdx.x;
    const int c = t & 15;
    const int i = blockIdx.x * 16 + (t >> 4);
    if (i >= n) return;

    float frp[8];
    #pragma unroll
    for (int j = 0; j < 8; ++j) {
        float f = fminf(fmaxf(freqs[c * 8 + j], 0.0f), 1.0f);
        frp[j] = __builtin_amdgcn_exp2f(f * 8.0f) - 0.5f;
    }
    const float c0 = coords[3 * (size_t)i + 0];
    const float c1 = coords[3 * (size_t)i + 1];
    const float c2 = coords[3 * (size_t)i + 2];
    const float pts0 = (c0 + 1.0f) * 127.5f;
    const float pts1 = (c1 + 1.0f) * 127.5f;
    const float pts2 = (c2 + 1.0f) * 127.5f;
    float acc = 0.0f;
    #pragma unroll
    for (int p = 0; p < 3; ++p) {
        const float sx = (p == 0) ? pts1 : pts0;
        const float sy = (p == 2) ? pts1 : pts2;
        const float pp = (p == 0) ? pts0 : ((p == 1) ? pts1 : pts2);
        const float ix = reflectf(sx);
        const float iy = reflectf(sy);
        const float x0f = floorf(ix), y0f = floorf(iy);
        const float wx = ix - x0f, wy = iy - y0f;
        int x0 = (int)x0f; x0 = min(max(x0, 0), RES - 1);
        int y0 = (int)y0f; y0 = min(max(y0, 0), RES - 1);
        const int x1 = min(x0 + 1, RES - 1);
        const int y1 = min(y0 + 1, RES - 1);
        const float w00 = (1.0f - wx) * (1.0f - wy);
        const float w01 = wx * (1.0f - wy);
        const float w10 = (1.0f - wx) * wy;
        const float w11 = wx * wy;
        const float Ap = (pp + 0.5f) * (1.0f / 512.0f);
        const size_t plane = (size_t)p * NCH * RES * RES;
        const int o00 = y0 * RES + x0, o01 = y0 * RES + x1;
        const int o10 = y1 * RES + x0, o11 = y1 * RES + x1;
        #pragma unroll
        for (int j = 0; j < 8; ++j) {
            const float* gq = grid + plane + (size_t)(c * 8 + j) * (RES * RES);
            const float coef = w00 * gq[o00] + w01 * gq[o01]
                             + w10 * gq[o10] + w11 * gq[o11];
            const float rr = __builtin_amdgcn_fractf(Ap * frp[j]);
            acc += coef * __builtin_amdgcn_cosf(rr);
        }
    }
    out[(size_t)i * NC + c] = 2.0f * acc;
}

extern "C" void kernel_launch(void* const* d_in, const int* in_sizes, int n_in,
                              void* d_out, int out_size, void* d_ws, size_t ws_size,
                              hipStream_t stream)
{
    const float* coords = (const float*)d_in[0];
    const float* grid   = (const float*)d_in[1];
    const float* freqs  = (const float*)d_in[2];
    float* out = (float*)d_out;
    const int n = in_sizes[0] / 3;

    // Workspace layout (16B-aligned): gridT must be immediately followed by
    // hist (the main kernel's weight-0 corner reads overrun gridT by <=64.5KB).
    const size_t gridT_b = (size_t)3 * RES * RES * NPK * sizeof(unsigned); // 50.33MB
    const size_t hist_b  = (size_t)NBINS * sizeof(unsigned);               // 128KB
    const size_t frp_b   = 128 * sizeof(float);
    const size_t rec_b   = (size_t)n * RECW * sizeof(unsigned);
    const size_t need = gridT_b + 2 * hist_b + frp_b + rec_b;

    const int blocks = (n + 15) / 16;

    if (ws_size >= need) {
        char* ws = (char*)d_ws;
        unsigned* gridT  = (unsigned*)ws;  ws += gridT_b;
        unsigned* hist   = (unsigned*)ws;  ws += hist_b;
        unsigned* cursor = (unsigned*)ws;  ws += hist_b;
        float*    frp    = (float*)ws;     ws += frp_b;
        unsigned* rec    = (unsigned*)ws;

        hipMemsetAsync(hist, 0, hist_b, stream);
        hipLaunchKernelGGL(fg_hist, dim3((n + 255) / 256), dim3(256), 0, stream,
                           coords, hist, n);
        hipLaunchKernelGGL(fg_transpose, dim3(2, RES, 3), dim3(256), 0, stream,
                           grid, gridT);
        hipLaunchKernelGGL(fg_scan, dim3(1), dim3(1024), 0, stream,
                           hist, cursor, freqs, frp);
        hipLaunchKernelGGL(fg_scatter, dim3((n + 255) / 256), dim3(256), 0, stream,
                           coords, cursor, rec, n);
        hipLaunchKernelGGL(fg_main_bf16, dim3(blocks), dim3(256), 0, stream,
                           gridT, frp, rec, out, n);
    } else {
        hipLaunchKernelGGL(fg_main_f32, dim3(blocks), dim3(256), 0, stream,
                           coords, grid, freqs, out, n);
    }
}

// Round 7
// 271.550 us; speedup vs baseline: 1.0075x; 1.0075x over previous
//
#include <hip/hip_runtime.h>

#define RES   256
#define NCH   128    // C*F
#define NC    16
#define NPK   64     // packed uint32 per (p,y,x) position = NCH/2
#define NBINS 32768  // 32^3 Morton cells
#define RECW  12     // uint32 words per point record (48B)

__device__ __forceinline__ unsigned f32_to_bf16_rne(float f) {
    unsigned u = __float_as_uint(f);
    return (u + 0x7FFFu + ((u >> 16) & 1u)) >> 16;
}
__device__ __forceinline__ float bf16_lo(unsigned w) { return __uint_as_float(w << 16); }
__device__ __forceinline__ float bf16_hi(unsigned w) { return __uint_as_float(w & 0xFFFF0000u); }
__device__ __forceinline__ float reflectf(float v) {
    float r = fabsf(v);
    r = fmodf(r, 510.0f);
    return (r > 255.0f) ? (510.0f - r) : r;
}
__device__ __forceinline__ unsigned spread5(unsigned v) {  // 5 bits -> stride 3
    return (v & 1u) | ((v & 2u) << 2) | ((v & 4u) << 4) | ((v & 8u) << 6) | ((v & 16u) << 8);
}
__device__ __forceinline__ int cell_of(int x0, int x1, int x2) {
    return (int)(spread5((unsigned)x0 >> 3) | (spread5((unsigned)x1 >> 3) << 1)
               | (spread5((unsigned)x2 >> 3) << 2));
}
__device__ __forceinline__ int point_cell(const float* __restrict__ coords, int i) {
    const int a = (int)reflectf((coords[3 * (size_t)i + 0] + 1.0f) * 127.5f);
    const int b = (int)reflectf((coords[3 * (size_t)i + 1] + 1.0f) * 127.5f);
    const int d = (int)reflectf((coords[3 * (size_t)i + 2] + 1.0f) * 127.5f);
    return cell_of(a, b, d);
}

// ---------------------------------------------------------------------------
// LDS-free transpose+pack, STORE-coalesced:
// f32 [3][128][256][256] -> bf16-pair uint32 [3][256][256][64].
// Per (p,y) slab there are 256 x * 16 chunks = 4096 uint4. u = x*16 + j,
// lane==u: consecutive lanes store consecutive 16B (1KB/wave, no write
// amplification). Reads: for each channel 8j+r, one 256-thread iteration
// consumes exactly one full 64B line (x0..x0+15) -> L1-served reuse.
// Coverage: gridDim.x(4) * KK(4) * 256 threads = 4096 u per slab.
// ---------------------------------------------------------------------------
__global__ __launch_bounds__(256) void fg_transpose(
    const float* __restrict__ in, unsigned* __restrict__ out)
{
    const int tid = threadIdx.x;
    const int y = blockIdx.y, p = blockIdx.z;
    const float* src = in + ((size_t)p * NCH * RES + y) * RES;
    uint4* dst = (uint4*)(out + (((size_t)p * RES + y) * RES) * NPK);

    #pragma unroll
    for (int kk = 0; kk < 4; ++kk) {
        const int u = (blockIdx.x * 4 + kk) * 256 + tid;   // 0..4095
        const int x = u >> 4;          // 0..255
        const int j = u & 15;          // chunk: channels 8j..8j+7
        const float* s = src + (size_t)(8 * j) * (RES * RES) + x;
        float v[8];
        #pragma unroll
        for (int r = 0; r < 8; ++r)
            v[r] = s[(size_t)r * (RES * RES)];
        uint4 w;
        w.x = f32_to_bf16_rne(v[0]) | (f32_to_bf16_rne(v[1]) << 16);
        w.y = f32_to_bf16_rne(v[2]) | (f32_to_bf16_rne(v[3]) << 16);
        w.z = f32_to_bf16_rne(v[4]) | (f32_to_bf16_rne(v[5]) << 16);
        w.w = f32_to_bf16_rne(v[6]) | (f32_to_bf16_rne(v[7]) << 16);
        dst[u] = w;
    }
}

// ---------------------------------------------------------------------------
// Morton-cell histogram
// ---------------------------------------------------------------------------
__global__ __launch_bounds__(256) void fg_hist(
    const float* __restrict__ coords, unsigned* __restrict__ hist, int n)
{
    const int i = blockIdx.x * 256 + threadIdx.x;
    if (i >= n) return;
    atomicAdd(&hist[point_cell(coords, i)], 1u);
}

// ---------------------------------------------------------------------------
// Exclusive scan over 32768 bins (one 1024-thread block) + frp precompute
// ---------------------------------------------------------------------------
__global__ __launch_bounds__(1024) void fg_scan(
    const unsigned* __restrict__ hist, unsigned* __restrict__ cursor,
    const float* __restrict__ freqs, float* __restrict__ frp)
{
    __shared__ unsigned wtot[16];
    const int t = threadIdx.x;
    const int lane = t & 63;
    const int wid = t >> 6;
    unsigned loc[32];
    unsigned sum = 0;
    #pragma unroll
    for (int k = 0; k < 8; ++k) {
        const uint4 u = ((const uint4*)hist)[t * 8 + k];
        loc[4 * k + 0] = u.x; loc[4 * k + 1] = u.y;
        loc[4 * k + 2] = u.z; loc[4 * k + 3] = u.w;
        sum += u.x + u.y + u.z + u.w;
    }
    unsigned v = sum;
    #pragma unroll
    for (int off = 1; off < 64; off <<= 1) {
        const unsigned u = __shfl_up(v, off);
        if (lane >= off) v += u;
    }
    if (lane == 63) wtot[wid] = v;
    __syncthreads();
    unsigned base = 0;
    #pragma unroll
    for (int w = 0; w < 16; ++w) base += (w < wid) ? wtot[w] : 0u;
    unsigned run = base + (v - sum);
    #pragma unroll
    for (int k = 0; k < 32; ++k) { cursor[t * 32 + k] = run; run += loc[k]; }
    if (t < 128) {
        const float f = fminf(fmaxf(freqs[t], 0.0f), 1.0f);
        frp[t] = __builtin_amdgcn_exp2f(f * 8.0f) - 0.5f;
    }
}

// ---------------------------------------------------------------------------
// Scatter: per-point record (3 plane byte-offsets, 3 weights, 3 phase coefs,
// orig index) written to Morton-sorted position. x1=x0+1 / y1=y0+1 over-read
// is weight-0 and lands in the hist region (finite uints) -> contributes 0.
// ---------------------------------------------------------------------------
__global__ __launch_bounds__(256) void fg_scatter(
    const float* __restrict__ coords, unsigned* __restrict__ cursor,
    unsigned* __restrict__ rec, int n)
{
    const int i = blockIdx.x * 256 + threadIdx.x;
    if (i >= n) return;
    int   x0[3];
    float w[3], A[3];
    #pragma unroll
    for (int k = 0; k < 3; ++k) {
        const float pts = (coords[3 * (size_t)i + k] + 1.0f) * 127.5f;
        const float r = reflectf(pts);
        const float fl = floorf(r);
        x0[k] = (int)fl;
        w[k]  = r - fl;
        A[k]  = (pts + 0.5f) * (1.0f / 512.0f);
    }
    const unsigned pos = atomicAdd(&cursor[cell_of(x0[0], x0[1], x0[2])], 1u);
    unsigned* o = rec + (size_t)pos * RECW;
    uint4 r0, r1, r2;
    r0.x = (unsigned)((x0[2] * 256 + x0[1]) * 256);            // plane0: y=d2,x=d1
    r0.y = (unsigned)((65536 + x0[2] * 256 + x0[0]) * 256);    // plane1: y=d2,x=d0
    r0.z = (unsigned)((131072 + x0[1] * 256 + x0[0]) * 256);   // plane2: y=d1,x=d0
    r0.w = __float_as_uint(w[0]);
    r1.x = __float_as_uint(w[1]);
    r1.y = __float_as_uint(w[2]);
    r1.z = __float_as_uint(A[0]);
    r1.w = __float_as_uint(A[1]);
    r2.x = __float_as_uint(A[2]);
    r2.y = (unsigned)i;
    r2.z = 0u; r2.w = 0u;
    *(uint4*)(o + 0) = r0;
    *(uint4*)(o + 4) = r1;
    *(uint4*)(o + 8) = r2;
}

// ---------------------------------------------------------------------------
// Main kernel: packed bf16 grid, Morton-sorted records, XCD-chunk swizzle.
// 16 lanes per point; lane c owns output channel c (q = c*8+f).
// ---------------------------------------------------------------------------
__global__ __launch_bounds__(256) void fg_main_bf16(
    const unsigned* __restrict__ grid,     // [3][256][256][64] bf16-pairs
    const float* __restrict__ frp_in,      // 128 precomputed (fr+0.5)
    const unsigned* __restrict__ rec,
    float* __restrict__ out, int n)
{
    const int t = threadIdx.x;
    const int c = t & 15;
    int b = blockIdx.x;
    {
        const int G = gridDim.x;
        const int chunk = G >> 3;
        const int lim = chunk << 3;
        if (b < lim) b = (b & 7) * chunk + (b >> 3);  // contiguous range per XCD
    }
    const int slot = b * 16 + (t >> 4);
    if (slot >= n) return;

    const unsigned* o = rec + (size_t)slot * RECW;
    const uint4 r0 = *(const uint4*)(o + 0);
    const uint4 r1 = *(const uint4*)(o + 4);
    const uint4 r2 = *(const uint4*)(o + 8);
    const unsigned off[3] = {r0.x, r0.y, r0.z};
    const float w0 = __uint_as_float(r0.w);
    const float w1 = __uint_as_float(r1.x);
    const float w2 = __uint_as_float(r1.y);
    const float A[3] = {__uint_as_float(r1.z), __uint_as_float(r1.w),
                        __uint_as_float(r2.x)};
    const int i = (int)r2.y;

    float frp[8];
    *(float4*)(frp + 0) = *(const float4*)(frp_in + c * 8 + 0);
    *(float4*)(frp + 4) = *(const float4*)(frp_in + c * 8 + 4);

    const char* gB = (const char*)grid;
    const unsigned claneoff = (unsigned)(c * 16);
    float acc = 0.0f;

    #pragma unroll
    for (int p = 0; p < 3; ++p) {
        const float wx = (p == 0) ? w1 : w0;
        const float wy = (p == 2) ? w1 : w2;
        const float ox = 1.0f - wx, oy = 1.0f - wy;
        const float w00 = ox * oy, w01 = wx * oy, w10 = ox * wy, w11 = wx * wy;

        const unsigned v0 = off[p] + claneoff;
        const unsigned v1 = v0 + 65536u;              // y+1 row
        const uint4 g00 = *(const uint4*)(gB + v0);
        const uint4 g01 = *(const uint4*)(gB + v0 + 256);  // x+1
        const uint4 g10 = *(const uint4*)(gB + v1);
        const uint4 g11 = *(const uint4*)(gB + v1 + 256);
        const unsigned a0[4] = {g00.x, g00.y, g00.z, g00.w};
        const unsigned a1[4] = {g01.x, g01.y, g01.z, g01.w};
        const unsigned a2[4] = {g10.x, g10.y, g10.z, g10.w};
        const unsigned a3[4] = {g11.x, g11.y, g11.z, g11.w};

        #pragma unroll
        for (int jj = 0; jj < 4; ++jj) {
            const float clo = w00 * bf16_lo(a0[jj]) + w01 * bf16_lo(a1[jj])
                            + w10 * bf16_lo(a2[jj]) + w11 * bf16_lo(a3[jj]);
            const float chi = w00 * bf16_hi(a0[jj]) + w01 * bf16_hi(a1[jj])
                            + w10 * bf16_hi(a2[jj]) + w11 * bf16_hi(a3[jj]);
            const float rl = __builtin_amdgcn_fractf(A[p] * frp[2 * jj + 0]);
            const float rh = __builtin_amdgcn_fractf(A[p] * frp[2 * jj + 1]);
            acc += clo * __builtin_amdgcn_cosf(rl);
            acc += chi * __builtin_amdgcn_cosf(rh);
        }
    }

    out[(size_t)i * NC + c] = 2.0f * acc;
}

// Fallback (no workspace): direct f32 channel-major gather.
__global__ __launch_bounds__(256) void fg_main_f32(
    const float* __restrict__ coords,
    const float* __restrict__ grid,
    const float* __restrict__ freqs,
    float* __restrict__ out, int n)
{
    const int t = threadIdx.x;
    const int c = t & 15;
    const int i = blockIdx.x * 16 + (t >> 4);
    if (i >= n) return;

    float frp[8];
    #pragma unroll
    for (int j = 0; j < 8; ++j) {
        float f = fminf(fmaxf(freqs[c * 8 + j], 0.0f), 1.0f);
        frp[j] = __builtin_amdgcn_exp2f(f * 8.0f) - 0.5f;
    }
    const float c0 = coords[3 * (size_t)i + 0];
    const float c1 = coords[3 * (size_t)i + 1];
    const float c2 = coords[3 * (size_t)i + 2];
    const float pts0 = (c0 + 1.0f) * 127.5f;
    const float pts1 = (c1 + 1.0f) * 127.5f;
    const float pts2 = (c2 + 1.0f) * 127.5f;
    float acc = 0.0f;
    #pragma unroll
    for (int p = 0; p < 3; ++p) {
        const float sx = (p == 0) ? pts1 : pts0;
        const float sy = (p == 2) ? pts1 : pts2;
        const float pp = (p == 0) ? pts0 : ((p == 1) ? pts1 : pts2);
        const float ix = reflectf(sx);
        const float iy = reflectf(sy);
        const float x0f = floorf(ix), y0f = floorf(iy);
        const float wx = ix - x0f, wy = iy - y0f;
        int x0 = (int)x0f; x0 = min(max(x0, 0), RES - 1);
        int y0 = (int)y0f; y0 = min(max(y0, 0), RES - 1);
        const int x1 = min(x0 + 1, RES - 1);
        const int y1 = min(y0 + 1, RES - 1);
        const float w00 = (1.0f - wx) * (1.0f - wy);
        const float w01 = wx * (1.0f - wy);
        const float w10 = (1.0f - wx) * wy;
        const float w11 = wx * wy;
        const float Ap = (pp + 0.5f) * (1.0f / 512.0f);
        const size_t plane = (size_t)p * NCH * RES * RES;
        const int o00 = y0 * RES + x0, o01 = y0 * RES + x1;
        const int o10 = y1 * RES + x0, o11 = y1 * RES + x1;
        #pragma unroll
        for (int j = 0; j < 8; ++j) {
            const float* gq = grid + plane + (size_t)(c * 8 + j) * (RES * RES);
            const float coef = w00 * gq[o00] + w01 * gq[o01]
                             + w10 * gq[o10] + w11 * gq[o11];
            const float rr = __builtin_amdgcn_fractf(Ap * frp[j]);
            acc += coef * __builtin_amdgcn_cosf(rr);
        }
    }
    out[(size_t)i * NC + c] = 2.0f * acc;
}

extern "C" void kernel_launch(void* const* d_in, const int* in_sizes, int n_in,
                              void* d_out, int out_size, void* d_ws, size_t ws_size,
                              hipStream_t stream)
{
    const float* coords = (const float*)d_in[0];
    const float* grid   = (const float*)d_in[1];
    const float* freqs  = (const float*)d_in[2];
    float* out = (float*)d_out;
    const int n = in_sizes[0] / 3;

    // Workspace layout (16B-aligned): gridT must be immediately followed by
    // hist (the main kernel's weight-0 corner reads overrun gridT by <=66KB).
    const size_t gridT_b = (size_t)3 * RES * RES * NPK * sizeof(unsigned); // 50.33MB
    const size_t hist_b  = (size_t)NBINS * sizeof(unsigned);               // 128KB
    const size_t frp_b   = 128 * sizeof(float);
    const size_t rec_b   = (size_t)n * RECW * sizeof(unsigned);
    const size_t need = gridT_b + 2 * hist_b + frp_b + rec_b;

    const int blocks = (n + 15) / 16;

    if (ws_size >= need) {
        char* ws = (char*)d_ws;
        unsigned* gridT  = (unsigned*)ws;  ws += gridT_b;
        unsigned* hist   = (unsigned*)ws;  ws += hist_b;
        unsigned* cursor = (unsigned*)ws;  ws += hist_b;
        float*    frp    = (float*)ws;     ws += frp_b;
        unsigned* rec    = (unsigned*)ws;

        hipMemsetAsync(hist, 0, hist_b, stream);
        hipLaunchKernelGGL(fg_hist, dim3((n + 255) / 256), dim3(256), 0, stream,
                           coords, hist, n);
        hipLaunchKernelGGL(fg_transpose, dim3(4, RES, 3), dim3(256), 0, stream,
                           grid, gridT);
        hipLaunchKernelGGL(fg_scan, dim3(1), dim3(1024), 0, stream,
                           hist, cursor, freqs, frp);
        hipLaunchKernelGGL(fg_scatter, dim3((n + 255) / 256), dim3(256), 0, stream,
                           coords, cursor, rec, n);
        hipLaunchKernelGGL(fg_main_bf16, dim3(blocks), dim3(256), 0, stream,
                           gridT, frp, rec, out, n);
    } else {
        hipLaunchKernelGGL(fg_main_f32, dim3(blocks), dim3(256), 0, stream,
                           coords, grid, freqs, out, n);
    }
}

// Round 8
// 250.870 us; speedup vs baseline: 1.0905x; 1.0824x over previous
//
#include <hip/hip_runtime.h>

#define RES   256
#define NCH   128    // C*F
#define NC    16
#define NPK   64     // packed uint32 per (p,y,x) position = NCH/2
#define NBINS 32768  // 32^3 Morton cells
#define RECW  12     // uint32 words per point record (48B)

__device__ __forceinline__ unsigned f32_to_bf16_rne(float f) {
    unsigned u = __float_as_uint(f);
    return (u + 0x7FFFu + ((u >> 16) & 1u)) >> 16;
}
__device__ __forceinline__ float bf16_lo(unsigned w) { return __uint_as_float(w << 16); }
__device__ __forceinline__ float bf16_hi(unsigned w) { return __uint_as_float(w & 0xFFFF0000u); }
__device__ __forceinline__ float reflectf(float v) {
    float r = fabsf(v);
    r = fmodf(r, 510.0f);
    return (r > 255.0f) ? (510.0f - r) : r;
}
__device__ __forceinline__ unsigned spread5(unsigned v) {  // 5 bits -> stride 3
    return (v & 1u) | ((v & 2u) << 2) | ((v & 4u) << 4) | ((v & 8u) << 6) | ((v & 16u) << 8);
}
__device__ __forceinline__ int cell_of(int x0, int x1, int x2) {
    return (int)(spread5((unsigned)x0 >> 3) | (spread5((unsigned)x1 >> 3) << 1)
               | (spread5((unsigned)x2 >> 3) << 2));
}
__device__ __forceinline__ int point_cell(const float* __restrict__ coords, int i) {
    const int a = (int)reflectf((coords[3 * (size_t)i + 0] + 1.0f) * 127.5f);
    const int b = (int)reflectf((coords[3 * (size_t)i + 1] + 1.0f) * 127.5f);
    const int d = (int)reflectf((coords[3 * (size_t)i + 2] + 1.0f) * 127.5f);
    return cell_of(a, b, d);
}

// ---------------------------------------------------------------------------
// LDS-tile transpose+pack, BOTH sides wave-contiguous:
// f32 [3][128][256][256] -> bf16-pair uint32 [3][256][256][64].
// Block = (x-quarter, y, p), tile = 128 channels x 64 x.
//   Read: wave = one channel-pair per iter, lanes = 64 consecutive x ->
//         each wave-load is a single 256B burst in one plane row (no DRAM
//         row scatter). Pack bf16 pair, store ldsT[qp][x] (stride 65:
//         bank=(qp+lane)%32, 2-way = free).
//   Write: u = xl*16+j, lane==u -> consecutive 16B global stores (1KB/wave);
//         uint4 gathered via 4 ds_read_b32, banks (4j+k+xl)%32 = 2-way free.
// ---------------------------------------------------------------------------
__global__ __launch_bounds__(256) void fg_transpose(
    const float* __restrict__ in, unsigned* __restrict__ out)
{
    __shared__ unsigned ldsT[64][65];     // [channel-pair][x], 16.6 KB
    const int tid = threadIdx.x;
    const int lane = tid & 63;
    const int wv = tid >> 6;              // 0..3
    const int x0 = blockIdx.x * 64;
    const int y = blockIdx.y, p = blockIdx.z;

    const float* src = in + ((size_t)p * NCH * RES + y) * RES + x0;
    #pragma unroll
    for (int it = 0; it < 16; ++it) {
        const int qp = it * 4 + wv;       // channel pair 0..63
        const float a = src[(size_t)(2 * qp + 0) * (RES * RES) + lane];
        const float b = src[(size_t)(2 * qp + 1) * (RES * RES) + lane];
        ldsT[qp][lane] = f32_to_bf16_rne(a) | (f32_to_bf16_rne(b) << 16);
    }
    __syncthreads();

    uint4* dst = (uint4*)(out + (((size_t)p * RES + y) * RES + x0) * NPK);
    #pragma unroll
    for (int it = 0; it < 4; ++it) {
        const int u = it * 256 + tid;     // 0..1023
        const int xl = u >> 4;            // 0..63
        const int j = u & 15;
        uint4 w;
        w.x = ldsT[4 * j + 0][xl];
        w.y = ldsT[4 * j + 1][xl];
        w.z = ldsT[4 * j + 2][xl];
        w.w = ldsT[4 * j + 3][xl];
        dst[u] = w;
    }
}

// ---------------------------------------------------------------------------
// Morton-cell histogram
// ---------------------------------------------------------------------------
__global__ __launch_bounds__(256) void fg_hist(
    const float* __restrict__ coords, unsigned* __restrict__ hist, int n)
{
    const int i = blockIdx.x * 256 + threadIdx.x;
    if (i >= n) return;
    atomicAdd(&hist[point_cell(coords, i)], 1u);
}

// ---------------------------------------------------------------------------
// Exclusive scan over 32768 bins (one 1024-thread block) + frp precompute
// ---------------------------------------------------------------------------
__global__ __launch_bounds__(1024) void fg_scan(
    const unsigned* __restrict__ hist, unsigned* __restrict__ cursor,
    const float* __restrict__ freqs, float* __restrict__ frp)
{
    __shared__ unsigned wtot[16];
    const int t = threadIdx.x;
    const int lane = t & 63;
    const int wid = t >> 6;
    unsigned loc[32];
    unsigned sum = 0;
    #pragma unroll
    for (int k = 0; k < 8; ++k) {
        const uint4 u = ((const uint4*)hist)[t * 8 + k];
        loc[4 * k + 0] = u.x; loc[4 * k + 1] = u.y;
        loc[4 * k + 2] = u.z; loc[4 * k + 3] = u.w;
        sum += u.x + u.y + u.z + u.w;
    }
    unsigned v = sum;
    #pragma unroll
    for (int off = 1; off < 64; off <<= 1) {
        const unsigned u = __shfl_up(v, off);
        if (lane >= off) v += u;
    }
    if (lane == 63) wtot[wid] = v;
    __syncthreads();
    unsigned base = 0;
    #pragma unroll
    for (int w = 0; w < 16; ++w) base += (w < wid) ? wtot[w] : 0u;
    unsigned run = base + (v - sum);
    #pragma unroll
    for (int k = 0; k < 32; ++k) { cursor[t * 32 + k] = run; run += loc[k]; }
    if (t < 128) {
        const float f = fminf(fmaxf(freqs[t], 0.0f), 1.0f);
        frp[t] = __builtin_amdgcn_exp2f(f * 8.0f) - 0.5f;
    }
}

// ---------------------------------------------------------------------------
// Scatter: per-point record (3 plane byte-offsets, 3 weights, 3 phase coefs,
// orig index) written to Morton-sorted position. x1=x0+1 / y1=y0+1 over-read
// is weight-0 and lands in the hist region (finite uints) -> contributes 0.
// ---------------------------------------------------------------------------
__global__ __launch_bounds__(256) void fg_scatter(
    const float* __restrict__ coords, unsigned* __restrict__ cursor,
    unsigned* __restrict__ rec, int n)
{
    const int i = blockIdx.x * 256 + threadIdx.x;
    if (i >= n) return;
    int   x0[3];
    float w[3], A[3];
    #pragma unroll
    for (int k = 0; k < 3; ++k) {
        const float pts = (coords[3 * (size_t)i + k] + 1.0f) * 127.5f;
        const float r = reflectf(pts);
        const float fl = floorf(r);
        x0[k] = (int)fl;
        w[k]  = r - fl;
        A[k]  = (pts + 0.5f) * (1.0f / 512.0f);
    }
    const unsigned pos = atomicAdd(&cursor[cell_of(x0[0], x0[1], x0[2])], 1u);
    unsigned* o = rec + (size_t)pos * RECW;
    uint4 r0, r1, r2;
    r0.x = (unsigned)((x0[2] * 256 + x0[1]) * 256);            // plane0: y=d2,x=d1
    r0.y = (unsigned)((65536 + x0[2] * 256 + x0[0]) * 256);    // plane1: y=d2,x=d0
    r0.z = (unsigned)((131072 + x0[1] * 256 + x0[0]) * 256);   // plane2: y=d1,x=d0
    r0.w = __float_as_uint(w[0]);
    r1.x = __float_as_uint(w[1]);
    r1.y = __float_as_uint(w[2]);
    r1.z = __float_as_uint(A[0]);
    r1.w = __float_as_uint(A[1]);
    r2.x = __float_as_uint(A[2]);
    r2.y = (unsigned)i;
    r2.z = 0u; r2.w = 0u;
    *(uint4*)(o + 0) = r0;
    *(uint4*)(o + 4) = r1;
    *(uint4*)(o + 8) = r2;
}

// ---------------------------------------------------------------------------
// Main kernel: packed bf16 grid, Morton-sorted records, XCD-chunk swizzle.
// 16 lanes per point; lane c owns output channel c (q = c*8+f).
// ---------------------------------------------------------------------------
__global__ __launch_bounds__(256) void fg_main_bf16(
    const unsigned* __restrict__ grid,     // [3][256][256][64] bf16-pairs
    const float* __restrict__ frp_in,      // 128 precomputed (fr+0.5)
    const unsigned* __restrict__ rec,
    float* __restrict__ out, int n)
{
    const int t = threadIdx.x;
    const int c = t & 15;
    int b = blockIdx.x;
    {
        const int G = gridDim.x;
        const int chunk = G >> 3;
        const int lim = chunk << 3;
        if (b < lim) b = (b & 7) * chunk + (b >> 3);  // contiguous range per XCD
    }
    const int slot = b * 16 + (t >> 4);
    if (slot >= n) return;

    const unsigned* o = rec + (size_t)slot * RECW;
    const uint4 r0 = *(const uint4*)(o + 0);
    const uint4 r1 = *(const uint4*)(o + 4);
    const uint4 r2 = *(const uint4*)(o + 8);
    const unsigned off[3] = {r0.x, r0.y, r0.z};
    const float w0 = __uint_as_float(r0.w);
    const float w1 = __uint_as_float(r1.x);
    const float w2 = __uint_as_float(r1.y);
    const float A[3] = {__uint_as_float(r1.z), __uint_as_float(r1.w),
                        __uint_as_float(r2.x)};
    const int i = (int)r2.y;

    float frp[8];
    *(float4*)(frp + 0) = *(const float4*)(frp_in + c * 8 + 0);
    *(float4*)(frp + 4) = *(const float4*)(frp_in + c * 8 + 4);

    const char* gB = (const char*)grid;
    const unsigned claneoff = (unsigned)(c * 16);
    float acc = 0.0f;

    #pragma unroll
    for (int p = 0; p < 3; ++p) {
        const float wx = (p == 0) ? w1 : w0;
        const float wy = (p == 2) ? w1 : w2;
        const float ox = 1.0f - wx, oy = 1.0f - wy;
        const float w00 = ox * oy, w01 = wx * oy, w10 = ox * wy, w11 = wx * wy;

        const unsigned v0 = off[p] + claneoff;
        const unsigned v1 = v0 + 65536u;              // y+1 row
        const uint4 g00 = *(const uint4*)(gB + v0);
        const uint4 g01 = *(const uint4*)(gB + v0 + 256);  // x+1
        const uint4 g10 = *(const uint4*)(gB + v1);
        const uint4 g11 = *(const uint4*)(gB + v1 + 256);
        const unsigned a0[4] = {g00.x, g00.y, g00.z, g00.w};
        const unsigned a1[4] = {g01.x, g01.y, g01.z, g01.w};
        const unsigned a2[4] = {g10.x, g10.y, g10.z, g10.w};
        const unsigned a3[4] = {g11.x, g11.y, g11.z, g11.w};

        #pragma unroll
        for (int jj = 0; jj < 4; ++jj) {
            const float clo = w00 * bf16_lo(a0[jj]) + w01 * bf16_lo(a1[jj])
                            + w10 * bf16_lo(a2[jj]) + w11 * bf16_lo(a3[jj]);
            const float chi = w00 * bf16_hi(a0[jj]) + w01 * bf16_hi(a1[jj])
                            + w10 * bf16_hi(a2[jj]) + w11 * bf16_hi(a3[jj]);
            const float rl = __builtin_amdgcn_fractf(A[p] * frp[2 * jj + 0]);
            const float rh = __builtin_amdgcn_fractf(A[p] * frp[2 * jj + 1]);
            acc += clo * __builtin_amdgcn_cosf(rl);
            acc += chi * __builtin_amdgcn_cosf(rh);
        }
    }

    out[(size_t)i * NC + c] = 2.0f * acc;
}

// Fallback (no workspace): direct f32 channel-major gather.
__global__ __launch_bounds__(256) void fg_main_f32(
    const float* __restrict__ coords,
    const float* __restrict__ grid,
    const float* __restrict__ freqs,
    float* __restrict__ out, int n)
{
    const int t = threadIdx.x;
    const int c = t & 15;
    const int i = blockIdx.x * 16 + (t >> 4);
    if (i >= n) return;

    float frp[8];
    #pragma unroll
    for (int j = 0; j < 8; ++j) {
        float f = fminf(fmaxf(freqs[c * 8 + j], 0.0f), 1.0f);
        frp[j] = __builtin_amdgcn_exp2f(f * 8.0f) - 0.5f;
    }
    const float c0 = coords[3 * (size_t)i + 0];
    const float c1 = coords[3 * (size_t)i + 1];
    const float c2 = coords[3 * (size_t)i + 2];
    const float pts0 = (c0 + 1.0f) * 127.5f;
    const float pts1 = (c1 + 1.0f) * 127.5f;
    const float pts2 = (c2 + 1.0f) * 127.5f;
    float acc = 0.0f;
    #pragma unroll
    for (int p = 0; p < 3; ++p) {
        const float sx = (p == 0) ? pts1 : pts0;
        const float sy = (p == 2) ? pts1 : pts2;
        const float pp = (p == 0) ? pts0 : ((p == 1) ? pts1 : pts2);
        const float ix = reflectf(sx);
        const float iy = reflectf(sy);
        const float x0f = floorf(ix), y0f = floorf(iy);
        const float wx = ix - x0f, wy = iy - y0f;
        int x0 = (int)x0f; x0 = min(max(x0, 0), RES - 1);
        int y0 = (int)y0f; y0 = min(max(y0, 0), RES - 1);
        const int x1 = min(x0 + 1, RES - 1);
        const int y1 = min(y0 + 1, RES - 1);
        const float w00 = (1.0f - wx) * (1.0f - wy);
        const float w01 = wx * (1.0f - wy);
        const float w10 = (1.0f - wx) * wy;
        const float w11 = wx * wy;
        const float Ap = (pp + 0.5f) * (1.0f / 512.0f);
        const size_t plane = (size_t)p * NCH * RES * RES;
        const int o00 = y0 * RES + x0, o01 = y0 * RES + x1;
        const int o10 = y1 * RES + x0, o11 = y1 * RES + x1;
        #pragma unroll
        for (int j = 0; j < 8; ++j) {
            const float* gq = grid + plane + (size_t)(c * 8 + j) * (RES * RES);
            const float coef = w00 * gq[o00] + w01 * gq[o01]
                             + w10 * gq[o10] + w11 * gq[o11];
            const float rr = __builtin_amdgcn_fractf(Ap * frp[j]);
            acc += coef * __builtin_amdgcn_cosf(rr);
        }
    }
    out[(size_t)i * NC + c] = 2.0f * acc;
}

extern "C" void kernel_launch(void* const* d_in, const int* in_sizes, int n_in,
                              void* d_out, int out_size, void* d_ws, size_t ws_size,
                              hipStream_t stream)
{
    const float* coords = (const float*)d_in[0];
    const float* grid   = (const float*)d_in[1];
    const float* freqs  = (const float*)d_in[2];
    float* out = (float*)d_out;
    const int n = in_sizes[0] / 3;

    // Workspace layout (16B-aligned): gridT must be immediately followed by
    // hist (the main kernel's weight-0 corner reads overrun gridT by <=66KB).
    const size_t gridT_b = (size_t)3 * RES * RES * NPK * sizeof(unsigned); // 50.33MB
    const size_t hist_b  = (size_t)NBINS * sizeof(unsigned);               // 128KB
    const size_t frp_b   = 128 * sizeof(float);
    const size_t rec_b   = (size_t)n * RECW * sizeof(unsigned);
    const size_t need = gridT_b + 2 * hist_b + frp_b + rec_b;

    const int blocks = (n + 15) / 16;

    if (ws_size >= need) {
        char* ws = (char*)d_ws;
        unsigned* gridT  = (unsigned*)ws;  ws += gridT_b;
        unsigned* hist   = (unsigned*)ws;  ws += hist_b;
        unsigned* cursor = (unsigned*)ws;  ws += hist_b;
        float*    frp    = (float*)ws;     ws += frp_b;
        unsigned* rec    = (unsigned*)ws;

        hipMemsetAsync(hist, 0, hist_b, stream);
        hipLaunchKernelGGL(fg_hist, dim3((n + 255) / 256), dim3(256), 0, stream,
                           coords, hist, n);
        hipLaunchKernelGGL(fg_transpose, dim3(4, RES, 3), dim3(256), 0, stream,
                           grid, gridT);
        hipLaunchKernelGGL(fg_scan, dim3(1), dim3(1024), 0, stream,
                           hist, cursor, freqs, frp);
        hipLaunchKernelGGL(fg_scatter, dim3((n + 255) / 256), dim3(256), 0, stream,
                           coords, cursor, rec, n);
        hipLaunchKernelGGL(fg_main_bf16, dim3(blocks), dim3(256), 0, stream,
                           gridT, frp, rec, out, n);
    } else {
        hipLaunchKernelGGL(fg_main_f32, dim3(blocks), dim3(256), 0, stream,
                           coords, grid, freqs, out, n);
    }
}